// Round 1
// 146.284 us; speedup vs baseline: 1.0064x; 1.0064x over previous
//
#include <hip/hip_runtime.h>
#include <hip/hip_fp16.h>
#include <math.h>

// Problem constants
constexpr int Bn = 256;
constexpr int Tn = 4096;
constexpr int BT = Bn * Tn;           // 1,048,576

// Chunk length halved (32 -> 16) to double block count: 4 blocks/CU, 12 waves/CU
// (3/SIMD) to hide the serial-scan dependency chains. Warmup stays 32 (accuracy).
constexpr int C   = 16;               // chunk length
constexpr int NF  = (Tn / C) * (Bn / 64);   // 1024 fused blocks (64b x 16t tiles)

struct __align__(8) h4 { __half2 x, y; };
typedef float v2f __attribute__((ext_vector_type(2)));

// ---- float2 helpers ----
__device__ __forceinline__ float2 f2(float a, float b){ return make_float2(a,b); }
__device__ __forceinline__ float2 f2s(float a){ return make_float2(a,a); }
__device__ __forceinline__ float2 f2mul(float2 a, float2 b){ return f2(a.x*b.x, a.y*b.y); }
__device__ __forceinline__ float2 f2fma(float2 a, float2 b, float2 c){
  return f2(fmaf(a.x,b.x,c.x), fmaf(a.y,b.y,c.y)); }

__device__ __forceinline__ __half2 h2c(float v){ return __float2half2_rn(v); }

// deg-5 odd poly sigmoid in packed fp16; err <3e-3 for |x|<=1.5
__device__ __forceinline__ __half2 sig2h(__half2 x) {
  __half2 x2 = __hmul2(x, x);
  __half2 p = __hfma2(x2, h2c(2.0833333e-3f), h2c(-2.0833333e-2f));
  p = __hfma2(x2, p, h2c(0.25f));
  return __hfma2(x, p, h2c(0.5f));
}
// Pade [5/4] tanh in packed fp16 (f32 rcp); err ~1e-3 for |x|<=2.5
__device__ __forceinline__ __half2 tanh2h(__half2 x) {
  __half2 x2 = __hmul2(x, x);
  __half2 num = __hfma2(x2, __hadd2(x2, h2c(105.f)), h2c(945.f));
  __half2 den = __hfma2(x2, __hfma2(x2, h2c(15.f), h2c(420.f)), h2c(945.f));
  float2 df = __half22float2(den);
  __half2 rd = __floats2half2_rn(__builtin_amdgcn_rcpf(df.x),
                                 __builtin_amdgcn_rcpf(df.y));
  return __hmul2(__hmul2(x, num), rd);
}

// -------------------- Kernel 1: precompute + transpose to [T][B], fp16 --------------------
__global__ __launch_bounds__(256) void k1_pre(
    const float* __restrict__ x,
    const float* __restrict__ fc1_w, const float* __restrict__ fc1_b,
    const float* __restrict__ fc2_w, const float* __restrict__ fc2_b,
    const float* __restrict__ w_ih,  const float* __restrict__ b_ih,
    const float* __restrict__ b_hh,
    h4* __restrict__ grz, __half2* __restrict__ gn, __half2* __restrict__ E)
{
  __shared__ h4      Lg[16][17];
  __shared__ __half2 Ln[16][17];
  __shared__ __half2 LE[16][17];
  int tid = threadIdx.x;
  int btile = blockIdx.x >> 8;        // 0..15
  int ttile = blockIdx.x & 255;       // 0..255

  {
    int bl = tid >> 4, tl = tid & 15;
    int b = btile * 16 + bl, t = ttile * 16 + tl;
    const float* xp = x + ((size_t)b * Tn + t) * 3;
    float x0 = xp[0], x1 = xp[1], x2 = xp[2];

    float gr0 = fmaf(x2, w_ih[2],  fmaf(x1, w_ih[1],  fmaf(x0, w_ih[0],  b_ih[0] + b_hh[0])));
    float gr1 = fmaf(x2, w_ih[5],  fmaf(x1, w_ih[4],  fmaf(x0, w_ih[3],  b_ih[1] + b_hh[1])));
    float gz0 = fmaf(x2, w_ih[8],  fmaf(x1, w_ih[7],  fmaf(x0, w_ih[6],  b_ih[2] + b_hh[2])));
    float gz1 = fmaf(x2, w_ih[11], fmaf(x1, w_ih[10], fmaf(x0, w_ih[9],  b_ih[3] + b_hh[3])));
    float gn0 = fmaf(x2, w_ih[14], fmaf(x1, w_ih[13], fmaf(x0, w_ih[12], b_ih[4])));
    float gn1 = fmaf(x2, w_ih[17], fmaf(x1, w_ih[16], fmaf(x0, w_ih[15], b_ih[5])));

    float zk0 = fc2_b[0], zk1 = fc2_b[1];
#pragma unroll
    for (int u = 0; u < 8; ++u) {
      float a = fmaf(x2, fc1_w[u*3+2], fmaf(x1, fc1_w[u*3+1], fmaf(x0, fc1_w[u*3+0], fc1_b[u])));
      float e2 = __expf(2.0f * a);
      float th = 1.0f - 2.0f * __builtin_amdgcn_rcpf(1.0f + e2);
      zk0 = fmaf(th, fc2_w[u], zk0);
      zk1 = fmaf(th, fc2_w[8 + u], zk1);
    }
    float m = fmaxf(zk0, zk1);
    h4 g; g.x = __float22half2_rn(f2(gr0, gr1)); g.y = __float22half2_rn(f2(gz0, gz1));
    Lg[tl][bl] = g;
    Ln[tl][bl] = __float22half2_rn(f2(gn0, gn1));
    LE[tl][bl] = __float22half2_rn(f2(__expf(zk0 - m), __expf(zk1 - m)));
  }
  __syncthreads();
  {
    int tl = tid >> 4, bl = tid & 15;
    int b = btile * 16 + bl, t = ttile * 16 + tl;
    size_t o = (size_t)t * Bn + b;
    grz[o] = Lg[tl][bl];
    gn[o]  = Ln[tl][bl];
    E[o]   = LE[tl][bl];
  }
}

// ---- scan macros (SROA-safe: constant-indexed local arrays; LDS result tiles) ----
// BASE/TB are ABSOLUTE t indices.
#define GRU_LOAD(BG, BN_, BASE) \
  { _Pragma("unroll") for (int i = 0; i < 8; ++i) { \
      BG[i] = gp[(size_t)((BASE) + i) * Bn]; BN_[i] = np[(size_t)((BASE) + i) * Bn]; } }

#define GRU_GROUP(BG, BN_, BASE, ST) \
  { _Pragma("unroll") for (int i = 0; i < 8; ++i) { \
      __half2 gA = BG[i].x, gB = BG[i].y, gN = BN_[i]; \
      __half2 h00 = __low2half2(hh), h11 = __high2half2(hh); \
      __half2 pr = __hfma2(h00, Wr0h, __hfma2(h11, Wr1h, gA)); \
      __half2 pz = __hfma2(h00, Wz0h, __hfma2(h11, Wz1h, gB)); \
      __half2 hn = __hfma2(h00, Wn0h, __hfma2(h11, Wn1h, Bnh)); \
      __half2 r = sig2h(pr), z = sig2h(pz); \
      __half2 n = tanh2h(__hfma2(r, hn, gN)); \
      hh = __hfma2(z, __hsub2(hh, n), n); \
      if (ST) Lh[(BASE) + i - t0][lane] = hh; \
  } }

#define ALP_LOAD(BUF, TB) \
  { _Pragma("unroll") for (int i = 0; i < 16; ++i) { BUF[i] = Ep[(size_t)((TB) + i) * Bn]; } }

#define ALP_GROUP(BUF, TB, ST, SK) \
  { _Pragma("unroll") for (int i = 0; i < 16; ++i) { \
      float2 e2 = __half22float2(BUF[i]); \
      if (!((SK) && i == 0)) { \
        av = f2mul(f2fma(f2s(av.y), A1v, f2mul(f2s(av.x), A0v)), e2); } \
      if (ST) La[(TB) + i - t0][lane] = __float22half2_rn(av); \
      if (i == 7 || i == 15) { \
        float rs = __builtin_amdgcn_rcpf(av.x + av.y); av.x *= rs; av.y *= rs; } \
  } }

#define BET_LOAD(BUF, TB, CL) \
  { _Pragma("unroll") for (int i = 0; i < 16; ++i) { \
      int li = (TB) + 1 - i; if ((CL) && i == 0) li = Tn - 1; \
      BUF[i] = Ep[(size_t)li * Bn]; } }

#define BET_GROUP(BUF, TB, ST, SK) \
  { _Pragma("unroll") for (int i = 0; i < 16; ++i) { \
      float2 e2 = __half22float2(BUF[i]); \
      if (!((SK) && i == 0)) { \
        float2 f = f2mul(e2, bv); \
        bv = f2fma(f2s(f.y), AB1, f2mul(f2s(f.x), AB0)); } \
      if (ST) Lb[(TB) - i - t0][lane] = __float22half2_rn(bv); \
      if (i == 7 || i == 15) { \
        float rs = __builtin_amdgcn_rcpf(bv.x + bv.y); bv.x *= rs; bv.y *= rs; } \
  } }

// -------------------- Kernel 2: fused scans (3 waves) + epilogue from LDS --------------------
__global__ __launch_bounds__(192) void k2_fused(
    const h4* __restrict__ grz, const __half2* __restrict__ gnp_,
    const __half2* __restrict__ E,
    const float* __restrict__ Q,
    const float* __restrict__ w_hh, const float* __restrict__ b_hh,
    const float* __restrict__ log_pi, const float* __restrict__ log_A,
    const float* __restrict__ Wg, const float* __restrict__ by,
    float* __restrict__ out_pi, float* __restrict__ out_g, float* __restrict__ out_lg)
{
  // padded [t][b] tiles: epilogue reads (lanes vary t) hit distinct banks; scan
  // writes (lanes vary b) are 2-way (free). 3 x 4.2 KB = 12.7 KB LDS -> 4 blocks/CU.
  __shared__ __half2 Lh[C][65], La[C][65], Lb[C][65];

  int tch = blockIdx.x >> 2;          // 0..255  t-chunk
  int bq  = blockIdx.x & 3;           // 0..3    b-quarter
  int t0  = tch * C;
  int wave = threadIdx.x >> 6;
  int lane = threadIdx.x & 63;
  int b = (bq << 6) + lane;

  if (wave == 0) {
    // ---------------- GRU (warmup up to 32; exact init when window reaches t=0) ----
    int warm = (t0 < 32) ? t0 : 32;   // t0 in {0,16}: exact h=0 boundary init
    int tstart = t0 - warm;
    int ng = (warm + C) >> 3;         // 8-step groups: 2, 4 or 6
    int wg = warm >> 3;               // non-storing warm groups
    const h4*      gp = grz  + b;
    const __half2* np = gnp_ + b;

    __half2 Wr0h = __floats2half2_rn(w_hh[0], w_hh[2]);
    __half2 Wr1h = __floats2half2_rn(w_hh[1], w_hh[3]);
    __half2 Wz0h = __floats2half2_rn(w_hh[4], w_hh[6]);
    __half2 Wz1h = __floats2half2_rn(w_hh[5], w_hh[7]);
    __half2 Wn0h = __floats2half2_rn(w_hh[8], w_hh[10]);
    __half2 Wn1h = __floats2half2_rn(w_hh[9], w_hh[11]);
    __half2 Bnh  = __floats2half2_rn(b_hh[4], b_hh[5]);

    __half2 hh = h2c(0.f);
    h4 AG[8], BG[8];
    __half2 AN[8], BN[8];
    GRU_LOAD(AG, AN, tstart);
    GRU_LOAD(BG, BN, tstart + 8);
    for (int g = 0; g < ng; g += 2) {
      { bool st = g >= wg; GRU_GROUP(AG, AN, tstart + g * 8, st); }
      if (g + 2 < ng) GRU_LOAD(AG, AN, tstart + (g + 2) * 8);
      { bool st = (g + 1) >= wg; GRU_GROUP(BG, BN, tstart + (g + 1) * 8, st); }
      if (g + 3 < ng) GRU_LOAD(BG, BN, tstart + (g + 3) * 8);
    }
  } else if (wave == 1) {
    // ---------------- alpha (forward, linear space; exact init when window reaches 0) --
    const __half2* Ep = E + b;

    float la0 = log_A[0], la1 = log_A[1], la2 = log_A[2], la3 = log_A[3];
    float m0 = fmaxf(la0, la1), m1 = fmaxf(la2, la3);
    float e00 = __expf(la0 - m0), e01 = __expf(la1 - m0);
    float e10 = __expf(la2 - m1), e11 = __expf(la3 - m1);
    float i0 = 1.0f / (e00 + e01), i1 = 1.0f / (e10 + e11);
    float2 A0v = f2(e00*i0, e01*i0), A1v = f2(e10*i1, e11*i1);

    int warm = (t0 < 32) ? t0 : 32;
    int tlo = t0 - warm;
    int ngroups = (warm + C) >> 4;    // 16-step groups: 1, 2 or 3
    int sg = warm >> 4;
    bool skip0 = (tlo == 0);          // exact a0 init at t=0

    float2 av;
    if (skip0) {
      float p0 = log_pi[0], p1 = log_pi[1];
      float mp = fmaxf(p0, p1);
      float2 E0 = __half22float2(Ep[0]);
      av = f2(__expf(p0 - mp) * E0.x, __expf(p1 - mp) * E0.y);
    } else {
      av = f2s(1.f);
    }

    __half2 EA[16], EB[16];
    ALP_LOAD(EA, tlo);
    if (ngroups > 1) ALP_LOAD(EB, tlo + 16);
    for (int g = 0; g < ngroups; g += 2) {
      { bool st = g >= sg; bool sk = skip0 && (g == 0);
        ALP_GROUP(EA, tlo + g * 16, st, sk); }
      if (g + 2 < ngroups) ALP_LOAD(EA, tlo + (g + 2) * 16);
      if (g + 1 < ngroups) {
        bool st = (g + 1) >= sg;
        ALP_GROUP(EB, tlo + (g + 1) * 16, st, false);
        if (g + 3 < ngroups) ALP_LOAD(EB, tlo + (g + 3) * 16);
      }
    }
  } else {
    // ---------------- beta (backward, linear space; exact init when window reaches T-1) --
    int t1 = t0 + C - 1;
    const __half2* Ep = E + b;

    float la0 = log_A[0], la1 = log_A[1], la2 = log_A[2], la3 = log_A[3];
    float m0 = fmaxf(la0, la1), m1 = fmaxf(la2, la3);
    float e00 = __expf(la0 - m0), e01 = __expf(la1 - m0);
    float e10 = __expf(la2 - m1), e11 = __expf(la3 - m1);
    float i0 = 1.0f / (e00 + e01), i1 = 1.0f / (e10 + e11);
    float2 AB0 = f2(e00*i0, e10*i1), AB1 = f2(e01*i0, e11*i1);

    int warm = ((Tn - 1 - t1) < 32) ? (Tn - 1 - t1) : 32;
    int thi = t1 + warm;
    int ngroups = (warm + C) >> 4;    // 1, 2 or 3
    int sg = warm >> 4;
    bool edge = (thi == Tn - 1);      // exact beta(T-1)=1 init; also clamps e-load

    float2 bv = f2s(1.f);

    __half2 FA[16], FB[16];
    BET_LOAD(FA, thi, edge);
    if (ngroups > 1) BET_LOAD(FB, thi - 16, false);
    for (int g = 0; g < ngroups; g += 2) {
      { bool st = g >= sg; bool sk = edge && (g == 0);
        BET_GROUP(FA, thi - g * 16, st, sk); }
      if (g + 2 < ngroups) BET_LOAD(FA, thi - (g + 2) * 16, false);
      if (g + 1 < ngroups) {
        bool st = (g + 1) >= sg;
        BET_GROUP(FB, thi - (g + 1) * 16, st, false);
        if (g + 3 < ngroups) BET_LOAD(FB, thi - (g + 3) * 16, false);
      }
    }
  }

  __syncthreads();

  // ---------------- epilogue: 192 threads over the 64b x 16t tile ----------------
  float wgr[20], byv[4];
#pragma unroll
  for (int i = 0; i < 20; ++i) wgr[i] = Wg[i];
#pragma unroll
  for (int i = 0; i < 4; ++i) byv[i] = by[i];

  int tid = threadIdx.x;
#pragma unroll
  for (int k = 0; k < 6; ++k) {
    int e = tid + k * 192;
    if (e < 64 * C) {
      int bl = e >> 4, tl = e & 15;       // lanes vary t -> coalesced [B][T] I/O
      int gb = (bq << 6) + bl;
      size_t idx = (size_t)gb * Tn + (t0 + tl);
      float2 hv = __half22float2(Lh[tl][bl]);
      float2 av = __half22float2(La[tl][bl]);
      float2 bv = __half22float2(Lb[tl][bl]);

      float p0 = av.x * bv.x, p1 = av.y * bv.y;
      float invs = 1.0f / (p0 + p1);
      float gamma0 = p0 * invs, gamma1 = p1 * invs;
      float lg0 = __logf(gamma0), lg1 = __logf(gamma1);

      float wh0[5], wh1[5];
#pragma unroll
      for (int a = 0; a < 5; ++a) {
        wh0[a] = fmaf(hv.y, wgr[5 + a],  hv.x * wgr[a]);
        wh1[a] = fmaf(hv.y, wgr[15 + a], hv.x * wgr[10 + a]);
      }
      float mx0 = wh0[0], mx1 = wh1[0];
#pragma unroll
      for (int a = 1; a < 5; ++a) { mx0 = fmaxf(mx0, wh0[a]); mx1 = fmaxf(mx1, wh1[a]); }
      float ex0[5], ex1[5];
      float s0 = 0.f, s1 = 0.f;
#pragma unroll
      for (int a = 0; a < 5; ++a) {
        ex0[a] = __expf(wh0[a] - mx0); s0 += ex0[a];
        ex1[a] = __expf(wh1[a] - mx1); s1 += ex1[a];
      }
      float r0 = 1.0f / s0, r1 = 1.0f / s1;
      float c0 = gamma0 * r0, c1 = gamma1 * r1;

      const v2f* q2 = (const v2f*)(Q + idx * 10);
      v2f qv[5];
#pragma unroll
      for (int a = 0; a < 5; ++a) qv[a] = __builtin_nontemporal_load(q2 + a);

      float V0 = fmaf(gamma1, byv[2], gamma0 * byv[0]);
      float V1 = fmaf(gamma1, byv[3], gamma0 * byv[1]);
      float ga[5];
#pragma unroll
      for (int a = 0; a < 5; ++a) {
        ga[a] = fmaf(c1, ex1[a], c0 * ex0[a]);
        V0 = fmaf(ga[a], qv[a].x, V0);
        V1 = fmaf(ga[a], qv[a].y, V1);
      }
#pragma unroll
      for (int a = 0; a < 5; ++a)
        __builtin_nontemporal_store(ga[a], out_g + idx * 5 + a);

      float mv = fmaxf(V0, V1);
      float l = mv + __logf(__expf(V0 - mv) + __expf(V1 - mv));
      v2f pi_v; pi_v.x = V0 - l; pi_v.y = V1 - l;
      v2f lg_v; lg_v.x = lg0;    lg_v.y = lg1;
      __builtin_nontemporal_store(pi_v, (v2f*)out_pi + idx);
      __builtin_nontemporal_store(lg_v, (v2f*)out_lg + idx);
    }
  }
}

extern "C" void kernel_launch(void* const* d_in, const int* in_sizes, int n_in,
                              void* d_out, int out_size, void* d_ws, size_t ws_size,
                              hipStream_t stream) {
  const float* x      = (const float*)d_in[0];
  const float* Q      = (const float*)d_in[1];
  const float* log_pi = (const float*)d_in[2];
  const float* log_A  = (const float*)d_in[3];
  const float* fc1_w  = (const float*)d_in[4];
  const float* fc1_b  = (const float*)d_in[5];
  const float* fc2_w  = (const float*)d_in[6];
  const float* fc2_b  = (const float*)d_in[7];
  const float* w_ih   = (const float*)d_in[8];
  const float* w_hh   = (const float*)d_in[9];
  const float* b_ih   = (const float*)d_in[10];
  const float* b_hh   = (const float*)d_in[11];
  const float* Wg     = (const float*)d_in[12];
  const float* by     = (const float*)d_in[13];

  // ws layout (bytes, [T][B] transposed, fp16):
  // grz h4[BT] (8B) | gn half2[BT] (4B) | E half2[BT] (4B)   = 16 B/elem
  char* ws = (char*)d_ws;
  h4*      grz = (h4*)ws;
  __half2* gn  = (__half2*)(ws + (size_t)8  * BT);
  __half2* E   = (__half2*)(ws + (size_t)12 * BT);
  float* out = (float*)d_out;

  k1_pre<<<BT / 256, 256, 0, stream>>>(x, fc1_w, fc1_b, fc2_w, fc2_b, w_ih, b_ih, b_hh, grz, gn, E);
  k2_fused<<<NF, 192, 0, stream>>>(grz, gn, E, Q, w_hh, b_hh, log_pi, log_A, Wg, by,
                                   out, out + (size_t)2 * BT, out + (size_t)7 * BT);
}